// Round 3
// baseline (1871.025 us; speedup 1.0000x reference)
//
#include <hip/hip_runtime.h>
#include <cfloat>
#include <climits>

#define DDIM 64
#define KSEL 16

// ---------------------------------------------------------------------------
// numpy pairwise-sum emulation for n=64 contiguous f32, AVX512 npyv path:
//   sum0..3 = p[0:16], p[16:32], p[32:48], p[48:64]
//   lane    = (sum0+sum1)+(sum2+sum3)
//   res     = _mm512_reduce_add_ps(lane)  (halving tree: j+8, j+4, (0+2)+(1+3))
// All ops rounded f32, no FMA contraction (__fadd_rn/__fmul_rn).
// ---------------------------------------------------------------------------
__device__ __forceinline__ float np_sum64(const float* p) {
  float lane[16];
#pragma unroll
  for (int j = 0; j < 16; ++j)
    lane[j] = __fadd_rn(__fadd_rn(p[j], p[16 + j]),
                        __fadd_rn(p[32 + j], p[48 + j]));
  float u[8];
#pragma unroll
  for (int j = 0; j < 8; ++j) u[j] = __fadd_rn(lane[j], lane[j + 8]);
  float w[4];
#pragma unroll
  for (int j = 0; j < 4; ++j) w[j] = __fadd_rn(u[j], u[j + 4]);
  return __fadd_rn(__fadd_rn(w[0], w[2]), __fadd_rn(w[1], w[3]));
}

// ---------------------------------------------------------------------------
// Kernel 1: row norms emulating np.sum(a*a, axis=1) in f32
// ---------------------------------------------------------------------------
__global__ __launch_bounds__(256) void knn_norms_np(
    const float* __restrict__ keys, const float* __restrict__ queries,
    int Nk, int Nq, float* __restrict__ k2, float* __restrict__ q2) {
  int i = blockIdx.x * 256 + threadIdx.x;
  if (i >= Nk + Nq) return;
  const float* row = (i < Nk) ? keys + (size_t)i * DDIM
                              : queries + (size_t)(i - Nk) * DDIM;
  float p[DDIM];
#pragma unroll
  for (int t = 0; t < DDIM; ++t) p[t] = __fmul_rn(row[t], row[t]);
  float s = np_sum64(p);
  if (i < Nk) k2[i] = s; else q2[i - Nk] = s;
}

// ---------------------------------------------------------------------------
// Kernel 2: per-(key, query-slice) partial top-16 with np-emulated f32 d2.
//   dot  = sequential fmaf over k=0..63 (BLAS sgemm microkernel order)
//   d2   = round(round(k2 + q2[j]) - 2*dot)
// 4-query interleave for FMA ILP; per-query chain order preserved.
// ---------------------------------------------------------------------------
__global__ __launch_bounds__(256) void knn_partial_np(
    const float* __restrict__ keys, const float* __restrict__ queries,
    const float* __restrict__ k2a, const float* __restrict__ q2a,
    int Nk, int Nq, int nkb, int S, int QS,
    float* __restrict__ pd, int* __restrict__ pi) {
  int kb = blockIdx.x % nkb;
  int sl = blockIdx.x / nkb;
  int key = kb * 256 + (int)threadIdx.x;
  if (key >= Nk) return;

  float kreg[DDIM];
  const float4* kp = reinterpret_cast<const float4*>(keys + (size_t)key * DDIM);
#pragma unroll
  for (int t = 0; t < 16; ++t) {
    float4 v = kp[t];
    kreg[4 * t + 0] = v.x; kreg[4 * t + 1] = v.y;
    kreg[4 * t + 2] = v.z; kreg[4 * t + 3] = v.w;
  }
  float myk2 = k2a[key];

  float bd[KSEL];
  int   bi[KSEL];
#pragma unroll
  for (int p = 0; p < KSEL; ++p) { bd[p] = FLT_MAX; bi[p] = INT_MAX; }

  int j0 = sl * QS;
  int j1 = (j0 + QS < Nq) ? (j0 + QS) : Nq;

  for (int j = j0; j < j1; j += 4) {
    const float4* q40 = reinterpret_cast<const float4*>(queries + (size_t)(j + 0) * DDIM);
    const float4* q41 = reinterpret_cast<const float4*>(queries + (size_t)(j + 1) * DDIM);
    const float4* q42 = reinterpret_cast<const float4*>(queries + (size_t)(j + 2) * DDIM);
    const float4* q43 = reinterpret_cast<const float4*>(queries + (size_t)(j + 3) * DDIM);
    float c0 = 0.f, c1 = 0.f, c2 = 0.f, c3 = 0.f;
#pragma unroll
    for (int t = 0; t < 16; ++t) {
      float4 a0 = q40[t], a1 = q41[t], a2 = q42[t], a3 = q43[t];
      float k0 = kreg[4 * t + 0], k1 = kreg[4 * t + 1];
      float k2v = kreg[4 * t + 2], k3 = kreg[4 * t + 3];
      c0 = fmaf(k0, a0.x, c0); c1 = fmaf(k0, a1.x, c1);
      c2 = fmaf(k0, a2.x, c2); c3 = fmaf(k0, a3.x, c3);
      c0 = fmaf(k1, a0.y, c0); c1 = fmaf(k1, a1.y, c1);
      c2 = fmaf(k1, a2.y, c2); c3 = fmaf(k1, a3.y, c3);
      c0 = fmaf(k2v, a0.z, c0); c1 = fmaf(k2v, a1.z, c1);
      c2 = fmaf(k2v, a2.z, c2); c3 = fmaf(k2v, a3.z, c3);
      c0 = fmaf(k3, a0.w, c0); c1 = fmaf(k3, a1.w, c1);
      c2 = fmaf(k3, a2.w, c2); c3 = fmaf(k3, a3.w, c3);
    }
    float dots[4] = {c0, c1, c2, c3};
#pragma unroll
    for (int u = 0; u < 4; ++u) {
      float s = __fadd_rn(myk2, q2a[j + u]);
      float d2 = __fsub_rn(s, __fmul_rn(2.0f, dots[u]));
      if (d2 < bd[KSEL - 1]) {
        float cd = d2; int ci = j + u;
#pragma unroll
        for (int p = 0; p < KSEL; ++p) {
          bool sm = cd < bd[p];
          float td = bd[p]; int ti = bi[p];
          bd[p] = sm ? cd : td; bi[p] = sm ? ci : ti;
          cd = sm ? td : cd;   ci = sm ? ti : ci;
        }
      }
    }
  }

  size_t base = ((size_t)key * S + sl) * KSEL;
#pragma unroll
  for (int p = 0; p < KSEL; ++p) { pd[base + p] = bd[p]; pi[base + p] = bi[p]; }
}

// ---------------------------------------------------------------------------
// Kernel 3: merge S partial lists per key -> final top-16 indices (as float).
// Lexicographic (d2, idx) = stable top_k tie semantics on exact-equal f32 bits.
// ---------------------------------------------------------------------------
__global__ __launch_bounds__(256) void knn_merge(
    const float* __restrict__ pd, const int* __restrict__ pi,
    int Nk, int S, float* __restrict__ outIdx) {
  int key = blockIdx.x * 256 + threadIdx.x;
  if (key >= Nk) return;
  float bd[KSEL];
  int   bi[KSEL];
#pragma unroll
  for (int p = 0; p < KSEL; ++p) { bd[p] = FLT_MAX; bi[p] = INT_MAX; }
  size_t base = (size_t)key * S * KSEL;
  int n = S * KSEL;
  for (int e = 0; e < n; ++e) {
    float d = pd[base + e]; int id = pi[base + e];
    bool ins = (d < bd[KSEL - 1]) || (d == bd[KSEL - 1] && id < bi[KSEL - 1]);
    if (ins) {
      float cd = d; int ci = id;
#pragma unroll
      for (int p = 0; p < KSEL; ++p) {
        bool sm = (cd < bd[p]) || (cd == bd[p] && ci < bi[p]);
        float td = bd[p]; int ti = bi[p];
        bd[p] = sm ? cd : td; bi[p] = sm ? ci : ti;
        cd = sm ? td : cd;   ci = sm ? ti : ci;
      }
    }
  }
#pragma unroll
  for (int p = 0; p < KSEL; ++p)
    outIdx[(size_t)key * KSEL + p] = (float)bi[p];
}

// ---------------------------------------------------------------------------
// Kernel 4: recompute distances sum((k-q)^2) in f64 (threshold is ~2% of max,
// far above f32-vs-f64 drift), emit f32.
// ---------------------------------------------------------------------------
__global__ __launch_bounds__(256) void knn_dist_d(
    const float* __restrict__ keys, const float* __restrict__ queries,
    const float* __restrict__ outIdx, int Nk, float* __restrict__ outDist) {
  int e = blockIdx.x * 256 + threadIdx.x;
  if (e >= Nk * KSEL) return;
  int key = e >> 4;
  int id = (int)outIdx[e];
  const float* kp = keys + (size_t)key * DDIM;
  const float* qp = queries + (size_t)id * DDIM;
  double s = 0.0;
#pragma unroll
  for (int t = 0; t < DDIM; ++t) {
    double d = (double)kp[t] - (double)qp[t];
    s = fma(d, d, s);
  }
  outDist[e] = (float)s;
}

// ---------------------------------------------------------------------------
extern "C" void kernel_launch(void* const* d_in, const int* in_sizes, int n_in,
                              void* d_out, int out_size, void* d_ws, size_t ws_size,
                              hipStream_t stream) {
  const float* keys    = (const float*)d_in[0];
  const float* queries = (const float*)d_in[1];
  int Nk = in_sizes[0] / DDIM;   // 8192
  int Nq = in_sizes[1] / DDIM;   // 32768
  float* out = (float*)d_out;

  // Workspace: pd[S*Nk*16] f32 | pi[S*Nk*16] i32 | k2[Nk] f32 | q2[Nq] f32
  size_t normBytes = (size_t)(Nk + Nq) * 4;
  int S = 32;
  while (S > 1 && (size_t)S * Nk * KSEL * 8 + normBytes > ws_size) S >>= 1;
  int QS = (Nq + S - 1) / S;         // Nq, S powers of two -> QS multiple of 4

  float* pd = (float*)d_ws;
  int*   pi = (int*)((char*)d_ws + (size_t)S * Nk * KSEL * 4);
  float* k2 = (float*)((char*)d_ws + (size_t)S * Nk * KSEL * 8);
  float* q2 = k2 + Nk;

  int nkb = (Nk + 255) / 256;

  knn_norms_np<<<(Nk + Nq + 255) / 256, 256, 0, stream>>>(keys, queries, Nk, Nq, k2, q2);
  knn_partial_np<<<nkb * S, 256, 0, stream>>>(keys, queries, k2, q2, Nk, Nq, nkb, S, QS, pd, pi);
  knn_merge<<<nkb, 256, 0, stream>>>(pd, pi, Nk, S, out);
  knn_dist_d<<<(Nk * KSEL + 255) / 256, 256, 0, stream>>>(keys, queries, out, Nk,
                                                          out + (size_t)Nk * KSEL);
}